// Round 2
// baseline (1593.891 us; speedup 1.0000x reference)
//
#include <hip/hip_runtime.h>
#include <hip/hip_bf16.h>

// TrackHead bf16-MFMA implementation (MI355X / gfx950).
//   q = MLP2(x), r = MLP2(ref_x)  -> GEMM1 (K=12544, relu) + GEMM2 (K=1024)
//   h = 2-layer LSTM over T=8     -> 16 dual-K gate GEMMs + 16 cell kernels
//   out = [0 | q @ h^T]           -> einsum kernel
// All GEMMs NT (A[M,K] x W[N,K]^T, K contiguous), bf16 inputs, fp32 accum.
// MFMA 16x16x32 bf16; C/D layout col=lane&15, row=(lane>>4)*4+reg (m89-verified).

typedef __bf16 bf16;
typedef __attribute__((ext_vector_type(8))) __bf16 bf16x8;
typedef __attribute__((ext_vector_type(4))) float f32x4;

#define DEVINL __device__ __forceinline__

DEVINL void gload16(const void* g, void* l) {
    // async global->LDS, 16B per lane; LDS dst is wave-uniform base + lane*16
    __builtin_amdgcn_global_load_lds(
        (const __attribute__((address_space(1))) void*)g,
        (__attribute__((address_space(3))) void*)l, 16, 0, 0);
}

// ---------------------------------------------------------------- fp32 -> bf16
__global__ __launch_bounds__(256) void cvt_kernel(
    const float* __restrict__ s, bf16* __restrict__ d, int n8) {
    const int stride = gridDim.x * 256;
    for (int i = blockIdx.x * 256 + threadIdx.x; i < n8; i += stride) {
        const float4* sp = (const float4*)s + (size_t)i * 2;
        const float4 u = sp[0], v = sp[1];
        bf16x8 o;
        o[0] = (bf16)u.x; o[1] = (bf16)u.y; o[2] = (bf16)u.z; o[3] = (bf16)u.w;
        o[4] = (bf16)v.x; o[5] = (bf16)v.y; o[6] = (bf16)v.z; o[7] = (bf16)v.w;
        *(bf16x8*)(d + (size_t)i * 8) = o;
    }
}

// ---------------------------------------------------------------- GEMM1
// C[m,n] = relu(A[m,:] . W[n,:] + bias[n]) -> bf16. A fp32 (reg-staged+cvt),
// W bf16 (global_load_lds). 128x128 tile, BK=32, 4 waves (2x2), acc 4x4 frags.
// Row-split: m0 < 4096 uses (Ar,Wr,br); else (Aq,Wq,bq).
__global__ __launch_bounds__(256) void gemm1_kernel(
    const float* __restrict__ Ar, const bf16* __restrict__ Wr, const float* __restrict__ br,
    const float* __restrict__ Aq, const bf16* __restrict__ Wq, const float* __restrict__ bq,
    bf16* __restrict__ C) {
    constexpr int K = 12544, N = 1024, BK = 32;
    __shared__ bf16 As[128][BK];   // 8 KB
    __shared__ bf16 Bs[128][BK];   // 8 KB
    const int n0 = blockIdx.x * 128, m0t = blockIdx.y * 128;
    const float* A; const bf16* W; const float* bias; int m0;
    if (m0t < 4096) { A = Ar; W = Wr; bias = br; m0 = m0t; }
    else            { A = Aq; W = Wq; bias = bq; m0 = m0t - 4096; }
    const int tid = threadIdx.x, lane = tid & 63, wid = tid >> 6;
    const int wr = wid >> 1, wc = wid & 1;
    // W staging: wave w stages 16-row groups 2w, 2w+1 (lane -> row, 16B chunk)
    const int wrow = wid * 32 + (lane >> 2);
    const int kcol = (lane & 3) * 8;       // element offset within BK
    f32x4 acc[4][4] = {};

    for (int k0 = 0; k0 < K; k0 += BK) {
        gload16(W + (size_t)(n0 + wrow) * K + k0 + kcol, &Bs[wid * 32][0]);
        gload16(W + (size_t)(n0 + wrow + 16) * K + k0 + kcol, &Bs[wid * 32 + 16][0]);
        // A: 128 rows x 32 k fp32 -> bf16; 512 8-elem chunks, 2 per thread
#pragma unroll
        for (int c2 = 0; c2 < 2; ++c2) {
            const int idx = c2 * 256 + tid;
            const int row = idx >> 2, kq = idx & 3;
            const float4* sp = (const float4*)(A + (size_t)(m0 + row) * K + k0 + kq * 8);
            const float4 u = sp[0], v = sp[1];
            bf16x8 o;
            o[0] = (bf16)u.x; o[1] = (bf16)u.y; o[2] = (bf16)u.z; o[3] = (bf16)u.w;
            o[4] = (bf16)v.x; o[5] = (bf16)v.y; o[6] = (bf16)v.z; o[7] = (bf16)v.w;
            *(bf16x8*)&As[row][kq * 8] = o;
        }
        __syncthreads();
        const int fr = lane & 15, kg = lane >> 4;
        bf16x8 af[4], bfr[4];
#pragma unroll
        for (int i = 0; i < 4; ++i) af[i] = *(const bf16x8*)&As[wr * 64 + i * 16 + fr][kg * 8];
#pragma unroll
        for (int j = 0; j < 4; ++j) bfr[j] = *(const bf16x8*)&Bs[wc * 64 + j * 16 + fr][kg * 8];
#pragma unroll
        for (int i = 0; i < 4; ++i)
#pragma unroll
            for (int j = 0; j < 4; ++j)
                acc[i][j] = __builtin_amdgcn_mfma_f32_16x16x32_bf16(af[i], bfr[j], acc[i][j], 0, 0, 0);
        __syncthreads();
    }
    const int fr = lane & 15, r4 = (lane >> 4) * 4;
#pragma unroll
    for (int j = 0; j < 4; ++j) {
        const int col = n0 + wc * 64 + j * 16 + fr;
        const float bv = bias[col];
#pragma unroll
        for (int i = 0; i < 4; ++i) {
            const int rbase = m0t + wr * 64 + i * 16 + r4;
#pragma unroll
            for (int r = 0; r < 4; ++r) {
                float v = acc[i][j][r] + bv;
                v = fmaxf(v, 0.f);
                C[(size_t)(rbase + r) * N + col] = (bf16)v;
            }
        }
    }
}

// ---------------------------------------------------------------- bf16 GEMM
// 64x128 tile, BK=32, 4 waves (2x2), wave-tile 32x64 (acc 2x4 frags).
// DUAL: C = A1@W1^T + A2@W2^T + b1 + b2 (LSTM gates, K1 both passes).
// OUTF32: write fp32 (gates) else bf16 (activations). No relu (last MLP layer).
template<bool DUAL, bool OUTF32>
__global__ __launch_bounds__(256) void gemm_bf_kernel(
    const bf16* __restrict__ A1, const bf16* __restrict__ W1,
    const bf16* __restrict__ A2, const bf16* __restrict__ W2,
    const float* __restrict__ b1, const float* __restrict__ b2,
    float* __restrict__ Cf, bf16* __restrict__ Cb, int K1, int N) {
    __shared__ bf16 As[64][32];    // 4 KB
    __shared__ bf16 Bs[128][32];   // 8 KB
    const int n0 = blockIdx.x * 128, m0 = blockIdx.y * 64;
    const int tid = threadIdx.x, lane = tid & 63, wid = tid >> 6;
    const int wr = wid >> 1, wc = wid & 1;
    const int arow = wid * 16 + (lane >> 2);
    const int brow = wid * 32 + (lane >> 2);
    const int kcol = (lane & 3) * 8;
    f32x4 acc[2][4] = {};
#pragma unroll
    for (int pass = 0; pass < (DUAL ? 2 : 1); ++pass) {
        const bf16* A = pass ? A2 : A1;
        const bf16* W = pass ? W2 : W1;
        for (int k0 = 0; k0 < K1; k0 += 32) {
            gload16(A + (size_t)(m0 + arow) * K1 + k0 + kcol, &As[wid * 16][0]);
            gload16(W + (size_t)(n0 + brow) * K1 + k0 + kcol, &Bs[wid * 32][0]);
            gload16(W + (size_t)(n0 + brow + 16) * K1 + k0 + kcol, &Bs[wid * 32 + 16][0]);
            __syncthreads();
            const int fr = lane & 15, kg = lane >> 4;
            bf16x8 af[2], bfr[4];
#pragma unroll
            for (int i = 0; i < 2; ++i) af[i] = *(const bf16x8*)&As[wr * 32 + i * 16 + fr][kg * 8];
#pragma unroll
            for (int j = 0; j < 4; ++j) bfr[j] = *(const bf16x8*)&Bs[wc * 64 + j * 16 + fr][kg * 8];
#pragma unroll
            for (int i = 0; i < 2; ++i)
#pragma unroll
                for (int j = 0; j < 4; ++j)
                    acc[i][j] = __builtin_amdgcn_mfma_f32_16x16x32_bf16(af[i], bfr[j], acc[i][j], 0, 0, 0);
            __syncthreads();
        }
    }
    const int fr = lane & 15, r4 = (lane >> 4) * 4;
#pragma unroll
    for (int j = 0; j < 4; ++j) {
        const int col = n0 + wc * 64 + j * 16 + fr;
        float bv = b1[col];
        if (DUAL) bv += b2[col];
#pragma unroll
        for (int i = 0; i < 2; ++i) {
            const int rbase = m0 + wr * 32 + i * 16 + r4;
#pragma unroll
            for (int r = 0; r < 4; ++r) {
                const float v = acc[i][j][r] + bv;
                if (OUTF32) Cf[(size_t)(rbase + r) * N + col] = v;
                else        Cb[(size_t)(rbase + r) * N + col] = (bf16)v;
            }
        }
    }
}

// ---------------------------------------------------------------- LSTM cell
// gates [512,4096] fp32, PyTorch order (i,f,g,o); c fp32 in/out; h bf16 out.
__global__ __launch_bounds__(256) void lstm_cell_kernel(
    const float* __restrict__ gates, bf16* __restrict__ h, float* __restrict__ c) {
    const int idx = blockIdx.x * 256 + threadIdx.x;  // 512*1024
    const int n = idx >> 10, j = idx & 1023;
    const float* g = gates + (size_t)n * 4096;
    const float gi = g[j], gf = g[j + 1024], gg = g[j + 2048], go = g[j + 3072];
    const float si = 1.f / (1.f + expf(-gi));
    const float sf = 1.f / (1.f + expf(-gf));
    const float so = 1.f / (1.f + expf(-go));
    const float cn = sf * c[idx] + si * tanhf(gg);
    c[idx] = cn;
    h[idx] = (bf16)(so * tanhf(cn));
}

// ---------------------------------------------------------------- einsum
// out[b,i,0]=0 ; out[b,i,1+k] = q[b*128+i,:] . h[b*64+k,:]  (bf16 in, fp32 out)
__global__ __launch_bounds__(256) void einsum_kernel(
    const bf16* __restrict__ q, const bf16* __restrict__ h, float* __restrict__ out) {
    const int bi = blockIdx.x, b = bi >> 7;
    const int tid = threadIdx.x, wv = tid >> 6, lane = tid & 63;
    const bf16* qr = q + (size_t)bi * 1024 + lane * 16;
    const bf16x8 qa = *(const bf16x8*)qr, qb = *(const bf16x8*)(qr + 8);
    float* o = out + (size_t)bi * 65;
#pragma unroll 1
    for (int kk = 0; kk < 16; ++kk) {
        const int k = wv * 16 + kk;
        const bf16* hr = h + (size_t)(b * 64 + k) * 1024 + lane * 16;
        const bf16x8 ha = *(const bf16x8*)hr, hb = *(const bf16x8*)(hr + 8);
        float s = 0.f;
#pragma unroll
        for (int i = 0; i < 8; ++i)
            s += (float)qa[i] * (float)ha[i] + (float)qb[i] * (float)hb[i];
#pragma unroll
        for (int off = 32; off; off >>= 1) s += __shfl_xor(s, off);
        if (lane == 0) o[1 + k] = s;
    }
    if (tid == 0) o[0] = 0.f;
}

// ---------------------------------------------------------------- launch
extern "C" void kernel_launch(void* const* d_in, const int* in_sizes, int n_in,
                              void* d_out, int out_size, void* d_ws, size_t ws_size,
                              hipStream_t stream) {
    (void)in_sizes; (void)n_in; (void)out_size; (void)ws_size;
    const float* x    = (const float*)d_in[0];   // [1024, 12544]
    const float* refx = (const float*)d_in[1];   // [8*512, 12544]
    const float* qW1  = (const float*)d_in[2];
    const float* qb1  = (const float*)d_in[3];
    const float* qW2  = (const float*)d_in[4];
    const float* qb2  = (const float*)d_in[5];
    const float* iW1  = (const float*)d_in[6];
    const float* ib1  = (const float*)d_in[7];
    const float* iW2  = (const float*)d_in[8];
    const float* ib2  = (const float*)d_in[9];
    const float* Wih1 = (const float*)d_in[10];
    const float* Whh1 = (const float*)d_in[11];
    const float* bih1 = (const float*)d_in[12];
    const float* bhh1 = (const float*)d_in[13];
    const float* Wih2 = (const float*)d_in[14];
    const float* Whh2 = (const float*)d_in[15];
    const float* bih2 = (const float*)d_in[16];
    const float* bhh2 = (const float*)d_in[17];

    constexpr int H = 1024, INF = 12544, NL = 512;
    constexpr size_t W1E = (size_t)H * INF;   // 12,845,056
    constexpr size_t W2E = (size_t)H * H;     // 1,048,576
    constexpr size_t WLE = (size_t)4 * H * H; // 4,194,304
    constexpr size_t ACTE = (size_t)5120 * H;
    constexpr size_t HE = (size_t)NL * H;

    char* p = (char*)d_ws;
    bf16* qW1b = (bf16*)p; p += W1E * 2;
    bf16* iW1b = (bf16*)p; p += W1E * 2;
    bf16* qW2b = (bf16*)p; p += W2E * 2;
    bf16* iW2b = (bf16*)p; p += W2E * 2;
    bf16* Wih1b = (bf16*)p; p += WLE * 2;
    bf16* Whh1b = (bf16*)p; p += WLE * 2;
    bf16* Wih2b = (bf16*)p; p += WLE * 2;
    bf16* Whh2b = (bf16*)p; p += WLE * 2;
    bf16* act1 = (bf16*)p; p += ACTE * 2;     // [5120,1024] post-relu
    bf16* act2 = (bf16*)p; p += ACTE * 2;     // [5120,1024] = [r(4096) ; q(1024)]
    bf16* h1 = (bf16*)p; p += HE * 2;
    bf16* h2 = (bf16*)p; p += HE * 2;
    float* c1 = (float*)p; p += HE * 4;
    float* c2 = (float*)p; p += HE * 4;
    float* gates = (float*)p; p += (size_t)NL * 4 * H * 4;

    // weights fp32 -> bf16 (once per call; harness restores inputs each call)
    const int CG = 1024;
    cvt_kernel<<<CG, 256, 0, stream>>>(qW1, qW1b, (int)(W1E / 8));
    cvt_kernel<<<CG, 256, 0, stream>>>(iW1, iW1b, (int)(W1E / 8));
    cvt_kernel<<<CG, 256, 0, stream>>>(qW2, qW2b, (int)(W2E / 8));
    cvt_kernel<<<CG, 256, 0, stream>>>(iW2, iW2b, (int)(W2E / 8));
    cvt_kernel<<<CG, 256, 0, stream>>>(Wih1, Wih1b, (int)(WLE / 8));
    cvt_kernel<<<CG, 256, 0, stream>>>(Whh1, Whh1b, (int)(WLE / 8));
    cvt_kernel<<<CG, 256, 0, stream>>>(Wih2, Wih2b, (int)(WLE / 8));
    cvt_kernel<<<CG, 256, 0, stream>>>(Whh2, Whh2b, (int)(WLE / 8));

    // zero h1,h2 (bf16) + c1,c2 (fp32) — contiguous 6 MB
    hipMemsetAsync(h1, 0, HE * 2 * 2 + HE * 4 * 2, stream);

    // GEMM1: act1 = relu([refx;x] @ [iW1;qW1]^T + b). grid x = n-tile (8) so
    // bid%8 pins each W n-panel (3.2 MB bf16) to one XCD's L2.
    dim3 g1(H / 128, 5120 / 128);  // (8, 40)
    gemm1_kernel<<<g1, 256, 0, stream>>>(refx, iW1b, ib1, x, qW1b, qb1, act1);

    // GEMM2 (K=1024, no relu): r part then q part
    gemm_bf_kernel<false, false><<<dim3(8, 4096 / 64), 256, 0, stream>>>(
        act1, iW2b, nullptr, nullptr, ib2, nullptr, nullptr, act2, H, H);
    gemm_bf_kernel<false, false><<<dim3(8, 1024 / 64), 256, 0, stream>>>(
        act1 + (size_t)4096 * H, qW2b, nullptr, nullptr, qb2, nullptr,
        nullptr, act2 + (size_t)4096 * H, H, H);

    // 2-layer LSTM over T=8: gates = [in,h]@[Wih,Whh]^T + bih + bhh
    dim3 gl(4096 / 128, NL / 64);  // (32, 8)
    for (int t = 0; t < 8; ++t) {
        const bf16* rt = act2 + (size_t)t * NL * H;
        gemm_bf_kernel<true, true><<<gl, 256, 0, stream>>>(
            rt, Wih1b, h1, Whh1b, bih1, bhh1, gates, nullptr, H, 4 * H);
        lstm_cell_kernel<<<NL * H / 256, 256, 0, stream>>>(gates, h1, c1);
        gemm_bf_kernel<true, true><<<gl, 256, 0, stream>>>(
            h1, Wih2b, h2, Whh2b, bih2, bhh2, gates, nullptr, H, 4 * H);
        lstm_cell_kernel<<<NL * H / 256, 256, 0, stream>>>(gates, h2, c2);
    }

    // out = [0 | q @ h2^T]
    einsum_kernel<<<1024, 256, 0, stream>>>(act2 + (size_t)4096 * H, h2, (float*)d_out);
}